// Round 20
// baseline (5919.401 us; speedup 1.0000x reference)
//
#include <hip/hip_runtime.h>

#define NSTATE 16
#define H1 75
#define CHUNK 480            // 160 triples = 80 pair-groups; %16==0 (gl2lds)
#define NTRIC (CHUNK / 3)    // 160
#define NGRP (NTRIC / 2)     // 80 groups of 2 triples
#define CFLOATS (NGRP * 128) // 10240 floats = 40 KB per buffer (8 i3 * 16)

// exact numpy-f32 prior: mul+add (NOT fma) layer 1, sequential-k FMA layer 2.
#define PRIOR_ONE(rxv, jj, dst)                               \
  {                                                           \
    float acc = 0.f;                                          \
    for (int k = 0; k < H1; ++k) {                            \
      float h = __fadd_rn(__fmul_rn((rxv), W1[k]), b1[k]);    \
      h = fmaxf(h, 0.f);                                      \
      acc = __fmaf_rn(h, W2[k * NSTATE + (jj)], acc);         \
    }                                                         \
    (dst) = __fadd_rn(acc, b2[(jj)]);                         \
  }

#define DPP_SWAP(x, CTRL) \
  __int_as_float(__builtin_amdgcn_mov_dpp(__float_as_int(x), (CTRL), 0xF, 0xF, true))

// async global->LDS, 16B per lane, wave-uniform LDS base (HW layout contract)
#define GL2LDS(g, l)                                              \
  __builtin_amdgcn_global_load_lds(                               \
      (const __attribute__((address_space(1))) void*)(g),         \
      (__attribute__((address_space(3))) void*)(l), 16, 0, 0)

// i3 location LUTs (K1's formula): pair for (ph,s) lives at i3_ph(s)*16 + 2ph.
// ph=0: rotl(s), ph=1: rotr(s), ph=2: s.
__device__ __constant__ int ROTL3[8] = {0, 2, 4, 6, 1, 3, 5, 7};
__device__ __constant__ int ROTR3[8] = {0, 4, 1, 5, 2, 6, 3, 7};
__device__ __constant__ int IDENT3[8] = {0, 1, 2, 3, 4, 5, 6, 7};

// one exact ACS step replay (matches wave-0 lane arithmetic bit-for-bit;
// r19-verified): u_out[s] = fminf(u_in[(2s+r)&7]-x, u_in[(2s+1-r)&7]-y).
#define REPLAY_STEP(UIN, UOUT, QB, I3LUT, PHOFF)                          \
  _Pragma("unroll")                                                       \
  for (int s_ = 0; s_ < 8; ++s_) {                                        \
    const int r_ = s_ >> 2;                                               \
    const float2 pr_ = *(const float2*)((QB) + (I3LUT)[s_] * 16 + (PHOFF)); \
    (UOUT)[s_] = fminf(__fsub_rn((UIN)[(2 * s_ + r_) & 7], pr_.x),        \
                       __fsub_rn((UIN)[(2 * s_ + 1 - r_) & 7], pr_.y));   \
  }

__device__ __forceinline__ float argmin_parity8(const float* u) {
  float m = u[0]; int arg = 0;
#pragma unroll
  for (int k = 1; k < 8; ++k) {
    if (u[k] < m) { m = u[k]; arg = k; }   // strict-<: first occurrence
  }
  return (float)(arg & 1);
}

// ---------- K1: priors, grid-wide, PAIR-GROUPED + pre-swapped (r18) --------
__global__ void priors_kernel(const float* __restrict__ rx,
                              const float* __restrict__ W1,
                              const float* __restrict__ b1,
                              const float* __restrict__ W2,
                              const float* __restrict__ b2,
                              float* __restrict__ q, int T, int tot) {
  const int id = blockIdx.x * 256 + threadIdx.x;  // id = t*16 + j
  if (id >= tot) return;
  const int t = id >> 4, j = id & 15;
  float val = 0.f;
  if (t < T) {
    const float rxv = rx[t];
    PRIOR_ONE(rxv, j, val);
  }
  const int tr = t / 3, ph = t - 3 * tr;
  const int n2 = tr >> 1, a = tr & 1;
  const int s = j >> 1, b = j & 1, r = (s >> 2) & 1;
  const int i3 = (ph == 0) ? (((s << 1) | (s >> 2)) & 7)
               : (ph == 1) ? (((s >> 1) | (s << 2)) & 7) : s;
  const int slot = a * 6 + 2 * ph + (b ^ r);
  q[(size_t)n2 * 128 + i3 * 16 + slot] = val;
}

// ---------- K2: serial ACS + copy + bits, 3 waves ---------------------------
// wave 0: r19 butterfly, but (a) hist store shifted to the PHASE-1 boundary
//         (slot d1=rotr(i3)) so it fills the min->dpp hazard gap, and
//         (b) ring reloads distributed between phases (hazard fillers).
// wave 1: async copy chunk c+1 global -> q_lds[1-p] (r12-proven).
// wave 2: per triple: load u@ph1, replay ph1+ph2 (exact ops), 3 argmin bits
//         at t=3n+1..3n+3; out[0] is the constant 0 (all-zero initial state).
__launch_bounds__(192, 1)
__global__ void acs3_kernel(const float* __restrict__ q,
                            float* __restrict__ hist_g,
                            float* __restrict__ out, int T, int nchunks) {
  __shared__ float q_lds[2][CFLOATS];       // 80 KB
  const int tid = (int)threadIdx.x;
  const int lane = tid & 63;
  const int wid = tid >> 6;

  // ---- prologue: copy chunk 0 into q_lds[0] (all 192 threads) ----
  {
    const float4* src = (const float4*)q;
    float4* dst = (float4*)&q_lds[0][0];
    for (int i = tid; i < CFLOATS / 4; i += 192) dst[i] = src[i];
  }
  __syncthreads();

  const int i3 = (lane & 3) | ((lane >> 1) & 4);
  const int rotr_i = ((i3 >> 1) | (i3 << 2)) & 7;  // state held at phase 1
  float w = 0.f;  // S[i] = u[i] at phase 0

  if (wid == 0) __builtin_amdgcn_s_setprio(3);

  for (int c = 0; c < nchunks; ++c) {
    const int p = c & 1;

    if (wid == 0) {
      // ---- wave 0: serial butterfly over 80 pair-groups ----
      const char* qptr = (const char*)&q_lds[p][0] + i3 * 64;
      float* hgp = hist_g + (size_t)p * (NTRIC * 8) + rotr_i;  // hist[tr][8]

      float4 rX[4], rY[4], rZ[4];  // ring: 4 groups (8 triples) in flight
#pragma unroll
      for (int g = 0; g < 4; ++g) {
        rX[g] = *(const float4*)(qptr + g * 512);
        rY[g] = *(const float4*)(qptr + g * 512 + 16);
        rZ[g] = *(const float4*)(qptr + g * 512 + 32);
      }
      for (int it = 0; it < NGRP / 4 - 1; ++it) {  // 19 iters: groups 0..75
#pragma unroll
        for (int g = 0; g < 4; ++g) {
          const float4 Xa = rX[g], Xb = rY[g], Xc = rZ[g];
          // triple A
          { const float wp = DPP_SWAP(w, 0xB1);   // ph0: lane^1
            w = fminf(__fsub_rn(w, Xa.x), __fsub_rn(wp, Xa.y)); }
          rX[g] = *(const float4*)(qptr + (g + 4) * 512);     // hazard filler
          hgp[g * 16] = w;                        // u @ ph1, slot d1
          { const float wp = DPP_SWAP(w, 0x4E);   // ph1: lane^2
            w = fminf(__fsub_rn(w, Xa.z), __fsub_rn(wp, Xa.w)); }
          rY[g] = *(const float4*)(qptr + (g + 4) * 512 + 16); // hazard filler
          { const float wp = DPP_SWAP(w, 0x128);  // ph2: lane^8
            w = fminf(__fsub_rn(w, Xb.x), __fsub_rn(wp, Xb.y)); }
          rZ[g] = *(const float4*)(qptr + (g + 4) * 512 + 32); // hazard filler
          // triple B
          { const float wp = DPP_SWAP(w, 0xB1);
            w = fminf(__fsub_rn(w, Xb.z), __fsub_rn(wp, Xb.w)); }
          hgp[g * 16 + 8] = w;                    // u @ ph1, slot d1
          { const float wp = DPP_SWAP(w, 0x4E);
            w = fminf(__fsub_rn(w, Xc.x), __fsub_rn(wp, Xc.y)); }
          { const float wp = DPP_SWAP(w, 0x128);
            w = fminf(__fsub_rn(w, Xc.z), __fsub_rn(wp, Xc.w)); }
        }
        qptr += 2048; hgp += 64;
      }
#pragma unroll
      for (int g = 0; g < 4; ++g) {  // epilogue: groups 76..79, no reload
        const float4 Xa = rX[g], Xb = rY[g], Xc = rZ[g];
        { const float wp = DPP_SWAP(w, 0xB1);
          w = fminf(__fsub_rn(w, Xa.x), __fsub_rn(wp, Xa.y)); }
        hgp[g * 16] = w;
        { const float wp = DPP_SWAP(w, 0x4E);
          w = fminf(__fsub_rn(w, Xa.z), __fsub_rn(wp, Xa.w)); }
        { const float wp = DPP_SWAP(w, 0x128);
          w = fminf(__fsub_rn(w, Xb.x), __fsub_rn(wp, Xb.y)); }
        { const float wp = DPP_SWAP(w, 0xB1);
          w = fminf(__fsub_rn(w, Xb.z), __fsub_rn(wp, Xb.w)); }
        hgp[g * 16 + 8] = w;
        { const float wp = DPP_SWAP(w, 0x4E);
          w = fminf(__fsub_rn(w, Xc.x), __fsub_rn(wp, Xc.y)); }
        { const float wp = DPP_SWAP(w, 0x128);
          w = fminf(__fsub_rn(w, Xc.z), __fsub_rn(wp, Xc.w)); }
      }
    } else if (wid == 1) {
      // ---- wave 1: async copy chunk c+1 global -> q_lds[1-p] ----
      if (c + 1 < nchunks) {
        const float* srcbase = q + (size_t)(c + 1) * CFLOATS + lane * 4;
        float* const ldsbase = &q_lds[1 - p][0];
#pragma unroll
        for (int i = 0; i < CFLOATS / 256; ++i) {   // 40 x 1KB, all in flight
          GL2LDS(srcbase + i * 256, ldsbase + i * 256);
        }
        asm volatile("s_waitcnt vmcnt(0)" ::: "memory");
      }
    } else {
      // ---- wave 2: bits for chunk c-1 (replay ph1,ph2 + argmin) ----
      if (c > 0) {
        const int cc = c - 1;
        const float* hh = hist_g + (size_t)(1 - p) * (NTRIC * 8);
        const float* qc = q + (size_t)cc * CFLOATS;
        for (int tr = lane; tr < NTRIC; tr += 64) {
          float u1[8], u2[8], u3[8];
          *(float4*)&u1[0] = *(const float4*)(hh + tr * 8);
          *(float4*)&u1[4] = *(const float4*)(hh + tr * 8 + 4);
          const float* qb = qc + (tr >> 1) * 128 + (tr & 1) * 6;
          REPLAY_STEP(u1, u2, qb, ROTR3, 2);    // ph1 -> u @ 3tr+2
          REPLAY_STEP(u2, u3, qb, IDENT3, 4);   // ph2 -> u @ 3tr+3
          const int t0 = cc * CHUNK + tr * 3;
          out[t0 + 1] = argmin_parity8(u1);
          out[t0 + 2] = argmin_parity8(u2);
          out[t0 + 3] = argmin_parity8(u3);     // may be (cc+1)*CHUNK: valid
        }
      }
    }
    __syncthreads();
  }

  // ---- epilogue: bits for the last chunk (all 192 threads) + out[0] ----
  {
    const int c = nchunks - 1;
    const int p = c & 1;
    const int base = c * CHUNK;
    const float* hh = hist_g + (size_t)p * (NTRIC * 8);
    const float* qc = q + (size_t)c * CFLOATS;
    for (int tr = tid; tr < NTRIC; tr += 192) {
      float u1[8], u2[8], u3[8];
      *(float4*)&u1[0] = *(const float4*)(hh + tr * 8);
      *(float4*)&u1[4] = *(const float4*)(hh + tr * 8 + 4);
      const float* qb = qc + (tr >> 1) * 128 + (tr & 1) * 6;
      REPLAY_STEP(u1, u2, qb, ROTR3, 2);
      REPLAY_STEP(u2, u3, qb, IDENT3, 4);
      const int t0 = base + tr * 3;
      if (t0 + 1 < T) out[t0 + 1] = argmin_parity8(u1);
      if (t0 + 2 < T) out[t0 + 2] = argmin_parity8(u2);
      if (t0 + 3 < T) out[t0 + 3] = argmin_parity8(u3);
    }
    if (tid == 0) out[0] = 0.f;  // all-zero initial state: argmin=0, parity 0
  }
}

// ---------- Fallback: round-8 single-kernel structure (PASSING lineage) -----
#define NPROD 960
__launch_bounds__(1024, 1)
__global__ void viterbi_bfly(const float* __restrict__ rx,
                             const float* __restrict__ W1,
                             const float* __restrict__ b1,
                             const float* __restrict__ W2,
                             const float* __restrict__ b2,
                             float* __restrict__ out, int T) {
  __shared__ float q_lds[2][CHUNK][NSTATE];
  __shared__ float hist[2][CHUNK][9];
  const int tid = (int)threadIdx.x;
  const int lane = tid & 63;
  const int j = tid & 15;
  const int nchunks = (T + CHUNK - 1) / CHUNK;
  {
    const int n0 = min(CHUNK, T);
    for (int id = tid; id < n0 * NSTATE; id += 1024) {
      const int tl = id >> 4;
      const float rxv = rx[tl];
      PRIOR_ONE(rxv, j, q_lds[0][tl][j]);
    }
  }
  __syncthreads();
  const int i3 = (lane & 3) | ((lane >> 1) & 4);
  const int rotr_i = ((i3 >> 1) | (i3 << 2)) & 7;
  const int rotl_i = ((i3 << 1) | (i3 >> 2)) & 7;
  const int s0 = rotr_i, s1 = rotl_i, s2 = i3;
  const int q0 = 2 * s0, q1 = 2 * s1, q2 = 2 * s2;
  const bool r0 = (s0 & 4) != 0, r1 = (s1 & 4) != 0, r2 = (s2 & 4) != 0;
  const int d0 = i3, d1 = rotr_i, d2 = rotl_i;
  const bool dumper = (lane < 16) && ((lane & 4) == 0);
  float w = 0.f;
  for (int c = 0; c < nchunks; ++c) {
    const int p = c & 1;
    const int base = c * CHUNK;
    const int nsteps = min(CHUNK, T - base);
    const int npad = ((nsteps + 2) / 3) * 3;
    if (tid < 64) {
      const float* qb = &q_lds[p][0][0];
      float2 f0 = *(const float2*)(qb + 0 * 16 + q0);
      float2 f1 = *(const float2*)(qb + 1 * 16 + q1);
      float2 f2 = *(const float2*)(qb + 2 * 16 + q2);
      for (int tl = 0; tl < npad; tl += 3) {
        const int nt = min(tl + 3, CHUNK - 3);
        float2 g0 = *(const float2*)(qb + (nt + 0) * 16 + q0);
        float2 g1 = *(const float2*)(qb + (nt + 1) * 16 + q1);
        float2 g2 = *(const float2*)(qb + (nt + 2) * 16 + q2);
        if (dumper) hist[p][tl][d0] = w;
        {
          const float wpp = DPP_SWAP(w, 0xB1);
          const float we = r0 ? wpp : w, wo = r0 ? w : wpp;
          w = fminf(__fsub_rn(we, f0.x), __fsub_rn(wo, f0.y));
        }
        if (dumper) hist[p][tl + 1][d1] = w;
        {
          const float wpp = DPP_SWAP(w, 0x4E);
          const float we = r1 ? wpp : w, wo = r1 ? w : wpp;
          w = fminf(__fsub_rn(we, f1.x), __fsub_rn(wo, f1.y));
        }
        if (dumper) hist[p][tl + 2][d2] = w;
        {
          const float wpp = DPP_SWAP(w, 0x128);
          const float we = r2 ? wpp : w, wo = r2 ? w : wpp;
          w = fminf(__fsub_rn(we, f2.x), __fsub_rn(wo, f2.y));
        }
        f0 = g0; f1 = g1; f2 = g2;
      }
    } else {
      const int nc = c + 1;
      if (nc < nchunks) {
        const int nbase = nc * CHUNK;
        const int nn = min(CHUNK, T - nbase);
        for (int id = tid - 64; id < nn * NSTATE; id += NPROD) {
          const int tl = id >> 4;
          const float rxv = rx[nbase + tl];
          PRIOR_ONE(rxv, j, q_lds[1 - p][tl][j]);
        }
      }
      if (c > 0) {
        const int tl = tid - 64;
        if (tl < CHUNK) {
          const float* h = hist[1 - p][tl];
          float m = h[0]; int arg = 0;
          if (h[1] < m) { m = h[1]; arg = 1; }
          if (h[2] < m) { m = h[2]; arg = 2; }
          if (h[3] < m) { m = h[3]; arg = 3; }
          if (h[4] < m) { m = h[4]; arg = 4; }
          if (h[5] < m) { m = h[5]; arg = 5; }
          if (h[6] < m) { m = h[6]; arg = 6; }
          if (h[7] < m) { m = h[7]; arg = 7; }
          out[(c - 1) * CHUNK + tl] = (float)(arg & 1);
        }
      }
    }
    __syncthreads();
  }
  {
    const int c = nchunks - 1;
    const int p = c & 1;
    const int base = c * CHUNK;
    const int nsteps = T - base;
    if (tid < nsteps) {
      const float* h = hist[p][tid];
      float m = h[0]; int arg = 0;
      if (h[1] < m) { m = h[1]; arg = 1; }
      if (h[2] < m) { m = h[2]; arg = 2; }
      if (h[3] < m) { m = h[3]; arg = 3; }
      if (h[4] < m) { m = h[4]; arg = 4; }
      if (h[5] < m) { m = h[5]; arg = 5; }
      if (h[6] < m) { m = h[6]; arg = 6; }
      if (h[7] < m) { m = h[7]; arg = 7; }
      out[base + tid] = (float)(arg & 1);
    }
  }
}

extern "C" void kernel_launch(void* const* d_in, const int* in_sizes, int n_in,
                              void* d_out, int out_size, void* d_ws, size_t ws_size,
                              hipStream_t stream) {
  const float* rx = (const float*)d_in[0];
  const float* W1 = (const float*)d_in[1];
  const float* b1 = (const float*)d_in[2];
  const float* W2 = (const float*)d_in[3];
  const float* b2 = (const float*)d_in[4];
  float* out = (float*)d_out;
  const int T = in_sizes[0];

  const int nchunks = (T + CHUNK - 1) / CHUNK;
  const int tot = nchunks * CHUNK * NSTATE;              // K1 thread count
  const size_t qfloats = (size_t)nchunks * CFLOATS;
  const size_t hfloats = (size_t)2 * NTRIC * 8;          // 2-deep global ring
  const size_t need = (qfloats + hfloats) * 4;

  if (ws_size >= need) {
    float* qws = (float*)d_ws;
    float* hist_g = qws + qfloats;
    priors_kernel<<<(tot + 255) / 256, 256, 0, stream>>>(
        rx, W1, b1, W2, b2, qws, T, tot);
    acs3_kernel<<<1, 192, 0, stream>>>(qws, hist_g, out, T, nchunks);
  } else {
    viterbi_bfly<<<1, 1024, 0, stream>>>(rx, W1, b1, W2, b2, out, T);
  }
}

// Round 21
// 5808.633 us; speedup vs baseline: 1.0191x; 1.0191x over previous
//
#include <hip/hip_runtime.h>

#define NSTATE 16
#define H1 75
#define CHUNK 480            // 160 triples = 80 pair-groups; %16==0 (gl2lds)
#define NTRIC (CHUNK / 3)    // 160
#define NGRP (NTRIC / 2)     // 80 groups of 2 triples
#define CFLOATS (NGRP * 128) // 10240 floats = 40 KB per buffer (8 i3 * 16)

// exact numpy-f32 prior: mul+add (NOT fma) layer 1, sequential-k FMA layer 2.
#define PRIOR_ONE(rxv, jj, dst)                               \
  {                                                           \
    float acc = 0.f;                                          \
    for (int k = 0; k < H1; ++k) {                            \
      float h = __fadd_rn(__fmul_rn((rxv), W1[k]), b1[k]);    \
      h = fmaxf(h, 0.f);                                      \
      acc = __fmaf_rn(h, W2[k * NSTATE + (jj)], acc);         \
    }                                                         \
    (dst) = __fadd_rn(acc, b2[(jj)]);                         \
  }

#define DPP_SWAP(x, CTRL) \
  __int_as_float(__builtin_amdgcn_mov_dpp(__float_as_int(x), (CTRL), 0xF, 0xF, true))

// async global->LDS, 16B per lane, wave-uniform LDS base (HW layout contract)
#define GL2LDS(g, l)                                              \
  __builtin_amdgcn_global_load_lds(                               \
      (const __attribute__((address_space(1))) void*)(g),         \
      (__attribute__((address_space(3))) void*)(l), 16, 0, 0)

// i3 location LUTs (K1's formula): pair for (ph,s) lives at i3_ph(s).
// ph=0: rotl(s), ph=1: rotr(s)  [compile-time; full unroll -> static indexing]
__device__ __constant__ int ROTL3[8] = {0, 2, 4, 6, 1, 3, 5, 7};
__device__ __constant__ int ROTR3[8] = {0, 4, 1, 5, 2, 6, 3, 7};

// one exact ACS step replay (matches wave-0 lane arithmetic bit-for-bit):
// u_out[s] = fminf(u_in[(2s+r)&7] - x, u_in[(2s+1-r)&7] - y), r = s>>2,
// (x,y) = pre-swapped pair at qb[i3_ph(s)*16 + phoff].
#define REPLAY_STEP(UIN, UOUT, QB, I3LUT, PHOFF)                          \
  _Pragma("unroll")                                                       \
  for (int s_ = 0; s_ < 8; ++s_) {                                        \
    const int r_ = s_ >> 2;                                               \
    const float2 pr_ = *(const float2*)((QB) + (I3LUT)[s_] * 16 + (PHOFF)); \
    (UOUT)[s_] = fminf(__fsub_rn((UIN)[(2 * s_ + r_) & 7], pr_.x),        \
                       __fsub_rn((UIN)[(2 * s_ + 1 - r_) & 7], pr_.y));   \
  }

__device__ __forceinline__ float argmin_parity8(const float* u) {
  float m = u[0]; int arg = 0;
#pragma unroll
  for (int k = 1; k < 8; ++k) {
    if (u[k] < m) { m = u[k]; arg = k; }   // strict-<: first occurrence
  }
  return (float)(arg & 1);
}

// ---------- K1: priors, grid-wide, PAIR-GROUPED + pre-swapped (r18) --------
__global__ void priors_kernel(const float* __restrict__ rx,
                              const float* __restrict__ W1,
                              const float* __restrict__ b1,
                              const float* __restrict__ W2,
                              const float* __restrict__ b2,
                              float* __restrict__ q, int T, int tot) {
  const int id = blockIdx.x * 256 + threadIdx.x;  // id = t*16 + j
  if (id >= tot) return;
  const int t = id >> 4, j = id & 15;
  float val = 0.f;
  if (t < T) {
    const float rxv = rx[t];
    PRIOR_ONE(rxv, j, val);
  }
  const int tr = t / 3, ph = t - 3 * tr;
  const int n2 = tr >> 1, a = tr & 1;
  const int s = j >> 1, b = j & 1, r = (s >> 2) & 1;
  const int i3 = (ph == 0) ? (((s << 1) | (s >> 2)) & 7)
               : (ph == 1) ? (((s >> 1) | (s << 2)) & 7) : s;
  const int slot = a * 6 + 2 * ph + (b ^ r);
  q[(size_t)n2 * 128 + i3 * 16 + slot] = val;
}

// ---------- K2: serial ACS + copy + bits, 3 waves ---------------------------
// wave 0: r18 butterfly but ONE hist store per triple (phase-0 boundary u,
//         slot i3, single address reg + imm offsets) — wave 2 replays
//         phases 1/2 from q (exact same ops/order).
// wave 1: async copy chunk c+1 global -> q_lds[1-p] (r12-proven).
// wave 2: per triple: load u8 + replay 2 steps + 3 argmin bits.
__launch_bounds__(192, 1)
__global__ void acs3_kernel(const float* __restrict__ q,
                            float* __restrict__ hist_g,
                            float* __restrict__ out, int T, int nchunks) {
  __shared__ float q_lds[2][CFLOATS];       // 80 KB
  const int tid = (int)threadIdx.x;
  const int lane = tid & 63;
  const int wid = tid >> 6;

  // ---- prologue: copy chunk 0 into q_lds[0] (all 192 threads) ----
  {
    const float4* src = (const float4*)q;
    float4* dst = (float4*)&q_lds[0][0];
    for (int i = tid; i < CFLOATS / 4; i += 192) dst[i] = src[i];
  }
  __syncthreads();

  const int i3 = (lane & 3) | ((lane >> 1) & 4);
  float w = 0.f;  // S[i] = u[i] at phase 0

  if (wid == 0) __builtin_amdgcn_s_setprio(3);

  for (int c = 0; c < nchunks; ++c) {
    const int p = c & 1;

    if (wid == 0) {
      // ---- wave 0: serial butterfly over 80 pair-groups ----
      const char* qptr = (const char*)&q_lds[p][0] + i3 * 64;
      float* hgp = hist_g + (size_t)p * (NTRIC * 8) + i3;  // hist[tr][8]

      float4 rX[4], rY[4], rZ[4];  // ring: 4 groups (8 triples) in flight
#pragma unroll
      for (int g = 0; g < 4; ++g) {
        rX[g] = *(const float4*)(qptr + g * 512);
        rY[g] = *(const float4*)(qptr + g * 512 + 16);
        rZ[g] = *(const float4*)(qptr + g * 512 + 32);
      }
      for (int it = 0; it < NGRP / 4 - 1; ++it) {  // 19 iters: groups 0..75
#pragma unroll
        for (int g = 0; g < 4; ++g) {
          const float4 Xa = rX[g], Xb = rY[g], Xc = rZ[g];
          rX[g] = *(const float4*)(qptr + (g + 4) * 512);
          rY[g] = *(const float4*)(qptr + (g + 4) * 512 + 16);
          rZ[g] = *(const float4*)(qptr + (g + 4) * 512 + 32);
          // triple A
          hgp[g * 16] = w;                        // pre-update u, slot i3
          { const float wp = DPP_SWAP(w, 0xB1);   // lane^1
            w = fminf(__fsub_rn(w, Xa.x), __fsub_rn(wp, Xa.y)); }
          { const float wp = DPP_SWAP(w, 0x4E);   // lane^2
            w = fminf(__fsub_rn(w, Xa.z), __fsub_rn(wp, Xa.w)); }
          { const float wp = DPP_SWAP(w, 0x128);  // lane^8 (row_ror:8)
            w = fminf(__fsub_rn(w, Xb.x), __fsub_rn(wp, Xb.y)); }
          // triple B
          hgp[g * 16 + 8] = w;
          { const float wp = DPP_SWAP(w, 0xB1);
            w = fminf(__fsub_rn(w, Xb.z), __fsub_rn(wp, Xb.w)); }
          { const float wp = DPP_SWAP(w, 0x4E);
            w = fminf(__fsub_rn(w, Xc.x), __fsub_rn(wp, Xc.y)); }
          { const float wp = DPP_SWAP(w, 0x128);
            w = fminf(__fsub_rn(w, Xc.z), __fsub_rn(wp, Xc.w)); }
        }
        qptr += 2048; hgp += 64;
      }
#pragma unroll
      for (int g = 0; g < 4; ++g) {  // epilogue: groups 76..79, no reload
        const float4 Xa = rX[g], Xb = rY[g], Xc = rZ[g];
        hgp[g * 16] = w;
        { const float wp = DPP_SWAP(w, 0xB1);
          w = fminf(__fsub_rn(w, Xa.x), __fsub_rn(wp, Xa.y)); }
        { const float wp = DPP_SWAP(w, 0x4E);
          w = fminf(__fsub_rn(w, Xa.z), __fsub_rn(wp, Xa.w)); }
        { const float wp = DPP_SWAP(w, 0x128);
          w = fminf(__fsub_rn(w, Xb.x), __fsub_rn(wp, Xb.y)); }
        hgp[g * 16 + 8] = w;
        { const float wp = DPP_SWAP(w, 0xB1);
          w = fminf(__fsub_rn(w, Xb.z), __fsub_rn(wp, Xb.w)); }
        { const float wp = DPP_SWAP(w, 0x4E);
          w = fminf(__fsub_rn(w, Xc.x), __fsub_rn(wp, Xc.y)); }
        { const float wp = DPP_SWAP(w, 0x128);
          w = fminf(__fsub_rn(w, Xc.z), __fsub_rn(wp, Xc.w)); }
      }
    } else if (wid == 1) {
      // ---- wave 1: async copy chunk c+1 global -> q_lds[1-p] ----
      if (c + 1 < nchunks) {
        const float* srcbase = q + (size_t)(c + 1) * CFLOATS + lane * 4;
        float* const ldsbase = &q_lds[1 - p][0];
#pragma unroll
        for (int i = 0; i < CFLOATS / 256; ++i) {   // 40 x 1KB, all in flight
          GL2LDS(srcbase + i * 256, ldsbase + i * 256);
        }
        asm volatile("s_waitcnt vmcnt(0)" ::: "memory");
      }
    } else {
      // ---- wave 2: bits for chunk c-1 (replay + strict-< argmin) ----
      if (c > 0) {
        const int cc = c - 1;
        const float* hh = hist_g + (size_t)(1 - p) * (NTRIC * 8);
        const float* qc = q + (size_t)cc * CFLOATS;
        for (int tr = lane; tr < NTRIC; tr += 64) {
          float u0[8], u1[8], u2[8];
          *(float4*)&u0[0] = *(const float4*)(hh + tr * 8);
          *(float4*)&u0[4] = *(const float4*)(hh + tr * 8 + 4);
          const float* qb = qc + (tr >> 1) * 128 + (tr & 1) * 6;
          REPLAY_STEP(u0, u1, qb, ROTL3, 0);   // phase 0 -> u at ph1
          REPLAY_STEP(u1, u2, qb, ROTR3, 2);   // phase 1 -> u at ph2
          const int t0 = cc * CHUNK + tr * 3;
          out[t0]     = argmin_parity8(u0);
          out[t0 + 1] = argmin_parity8(u1);
          out[t0 + 2] = argmin_parity8(u2);
        }
      }
    }
    __syncthreads();
  }

  // ---- epilogue: bits for the last chunk (all 192 threads) ----
  {
    const int c = nchunks - 1;
    const int p = c & 1;
    const int base = c * CHUNK;
    const int nsteps = T - base;
    const float* hh = hist_g + (size_t)p * (NTRIC * 8);
    const float* qc = q + (size_t)c * CFLOATS;
    for (int tr = tid; tr * 3 < nsteps; tr += 192) {
      float u0[8], u1[8], u2[8];
      *(float4*)&u0[0] = *(const float4*)(hh + tr * 8);
      *(float4*)&u0[4] = *(const float4*)(hh + tr * 8 + 4);
      const float* qb = qc + (tr >> 1) * 128 + (tr & 1) * 6;
      REPLAY_STEP(u0, u1, qb, ROTL3, 0);
      REPLAY_STEP(u1, u2, qb, ROTR3, 2);
      const int t0 = base + tr * 3;
      if (t0 < T)     out[t0]     = argmin_parity8(u0);
      if (t0 + 1 < T) out[t0 + 1] = argmin_parity8(u1);
      if (t0 + 2 < T) out[t0 + 2] = argmin_parity8(u2);
    }
  }
}

// ---------- Fallback: round-8 single-kernel structure (PASSING lineage) -----
#define NPROD 960
__launch_bounds__(1024, 1)
__global__ void viterbi_bfly(const float* __restrict__ rx,
                             const float* __restrict__ W1,
                             const float* __restrict__ b1,
                             const float* __restrict__ W2,
                             const float* __restrict__ b2,
                             float* __restrict__ out, int T) {
  __shared__ float q_lds[2][CHUNK][NSTATE];
  __shared__ float hist[2][CHUNK][9];
  const int tid = (int)threadIdx.x;
  const int lane = tid & 63;
  const int j = tid & 15;
  const int nchunks = (T + CHUNK - 1) / CHUNK;
  {
    const int n0 = min(CHUNK, T);
    for (int id = tid; id < n0 * NSTATE; id += 1024) {
      const int tl = id >> 4;
      const float rxv = rx[tl];
      PRIOR_ONE(rxv, j, q_lds[0][tl][j]);
    }
  }
  __syncthreads();
  const int i3 = (lane & 3) | ((lane >> 1) & 4);
  const int rotr_i = ((i3 >> 1) | (i3 << 2)) & 7;
  const int rotl_i = ((i3 << 1) | (i3 >> 2)) & 7;
  const int s0 = rotr_i, s1 = rotl_i, s2 = i3;
  const int q0 = 2 * s0, q1 = 2 * s1, q2 = 2 * s2;
  const bool r0 = (s0 & 4) != 0, r1 = (s1 & 4) != 0, r2 = (s2 & 4) != 0;
  const int d0 = i3, d1 = rotr_i, d2 = rotl_i;
  const bool dumper = (lane < 16) && ((lane & 4) == 0);
  float w = 0.f;
  for (int c = 0; c < nchunks; ++c) {
    const int p = c & 1;
    const int base = c * CHUNK;
    const int nsteps = min(CHUNK, T - base);
    const int npad = ((nsteps + 2) / 3) * 3;
    if (tid < 64) {
      const float* qb = &q_lds[p][0][0];
      float2 f0 = *(const float2*)(qb + 0 * 16 + q0);
      float2 f1 = *(const float2*)(qb + 1 * 16 + q1);
      float2 f2 = *(const float2*)(qb + 2 * 16 + q2);
      for (int tl = 0; tl < npad; tl += 3) {
        const int nt = min(tl + 3, CHUNK - 3);
        float2 g0 = *(const float2*)(qb + (nt + 0) * 16 + q0);
        float2 g1 = *(const float2*)(qb + (nt + 1) * 16 + q1);
        float2 g2 = *(const float2*)(qb + (nt + 2) * 16 + q2);
        if (dumper) hist[p][tl][d0] = w;
        {
          const float wpp = DPP_SWAP(w, 0xB1);
          const float we = r0 ? wpp : w, wo = r0 ? w : wpp;
          w = fminf(__fsub_rn(we, f0.x), __fsub_rn(wo, f0.y));
        }
        if (dumper) hist[p][tl + 1][d1] = w;
        {
          const float wpp = DPP_SWAP(w, 0x4E);
          const float we = r1 ? wpp : w, wo = r1 ? w : wpp;
          w = fminf(__fsub_rn(we, f1.x), __fsub_rn(wo, f1.y));
        }
        if (dumper) hist[p][tl + 2][d2] = w;
        {
          const float wpp = DPP_SWAP(w, 0x128);
          const float we = r2 ? wpp : w, wo = r2 ? w : wpp;
          w = fminf(__fsub_rn(we, f2.x), __fsub_rn(wo, f2.y));
        }
        f0 = g0; f1 = g1; f2 = g2;
      }
    } else {
      const int nc = c + 1;
      if (nc < nchunks) {
        const int nbase = nc * CHUNK;
        const int nn = min(CHUNK, T - nbase);
        for (int id = tid - 64; id < nn * NSTATE; id += NPROD) {
          const int tl = id >> 4;
          const float rxv = rx[nbase + tl];
          PRIOR_ONE(rxv, j, q_lds[1 - p][tl][j]);
        }
      }
      if (c > 0) {
        const int tl = tid - 64;
        if (tl < CHUNK) {
          const float* h = hist[1 - p][tl];
          float m = h[0]; int arg = 0;
          if (h[1] < m) { m = h[1]; arg = 1; }
          if (h[2] < m) { m = h[2]; arg = 2; }
          if (h[3] < m) { m = h[3]; arg = 3; }
          if (h[4] < m) { m = h[4]; arg = 4; }
          if (h[5] < m) { m = h[5]; arg = 5; }
          if (h[6] < m) { m = h[6]; arg = 6; }
          if (h[7] < m) { m = h[7]; arg = 7; }
          out[(c - 1) * CHUNK + tl] = (float)(arg & 1);
        }
      }
    }
    __syncthreads();
  }
  {
    const int c = nchunks - 1;
    const int p = c & 1;
    const int base = c * CHUNK;
    const int nsteps = T - base;
    if (tid < nsteps) {
      const float* h = hist[p][tid];
      float m = h[0]; int arg = 0;
      if (h[1] < m) { m = h[1]; arg = 1; }
      if (h[2] < m) { m = h[2]; arg = 2; }
      if (h[3] < m) { m = h[3]; arg = 3; }
      if (h[4] < m) { m = h[4]; arg = 4; }
      if (h[5] < m) { m = h[5]; arg = 5; }
      if (h[6] < m) { m = h[6]; arg = 6; }
      if (h[7] < m) { m = h[7]; arg = 7; }
      out[base + tid] = (float)(arg & 1);
    }
  }
}

extern "C" void kernel_launch(void* const* d_in, const int* in_sizes, int n_in,
                              void* d_out, int out_size, void* d_ws, size_t ws_size,
                              hipStream_t stream) {
  const float* rx = (const float*)d_in[0];
  const float* W1 = (const float*)d_in[1];
  const float* b1 = (const float*)d_in[2];
  const float* W2 = (const float*)d_in[3];
  const float* b2 = (const float*)d_in[4];
  float* out = (float*)d_out;
  const int T = in_sizes[0];

  const int nchunks = (T + CHUNK - 1) / CHUNK;
  const int tot = nchunks * CHUNK * NSTATE;              // K1 thread count
  const size_t qfloats = (size_t)nchunks * CFLOATS;
  const size_t hfloats = (size_t)2 * NTRIC * 8;          // 2-deep global ring
  const size_t need = (qfloats + hfloats) * 4;

  if (ws_size >= need) {
    float* qws = (float*)d_ws;
    float* hist_g = qws + qfloats;
    priors_kernel<<<(tot + 255) / 256, 256, 0, stream>>>(
        rx, W1, b1, W2, b2, qws, T, tot);
    acs3_kernel<<<1, 192, 0, stream>>>(qws, hist_g, out, T, nchunks);
  } else {
    viterbi_bfly<<<1, 1024, 0, stream>>>(rx, W1, b1, W2, b2, out, T);
  }
}